// Round 7
// baseline (154.571 us; speedup 1.0000x reference)
//
#include <hip/hip_runtime.h>
#include <math.h>

#define N 8192
#define D 128
#define NUM_CLASSES 64
#define POS_TH 0.8f   // ALPHA - MARGIN
#define ALPHAF 1.2f
#define TF 10.0f
#define NB 64               // N / 128 tile grid dim
#define NTILE 2080          // NB*(NB+1)/2 upper-tri tiles
#define GRIDP 512           // 2 blocks/CU x 256 CU; contiguous 4-5 tile ranges

typedef __attribute__((ext_vector_type(8))) short short8;   // 8 x bf16
typedef __attribute__((ext_vector_type(4))) float f32x4;

// ws layout (floats):
//  [0]       posAcc   (zeroed by prep)
//  [1]       ctr      (uint, zeroed by prep)
//  [2..8)    pad
//  [8..8+N)      rowW (zeroed by prep)
//  [8+N..8+2N)   rowN
//  [8+2N..8+4N)  lsq  (float2 {sq, label})
//  [8+4N.. )     ebf  (N*D bf16), offset (8+4N)*4 B, 16B-aligned

static __device__ __forceinline__ unsigned short f2bf(float x) {
    unsigned u = __float_as_uint(x);
    u = u + 0x7fffu + ((u >> 16) & 1u);   // RNE
    return (unsigned short)(u >> 16);
}

static __device__ __forceinline__ int tri_off(int b) {  // tiles before row b
    return b * NB - (b * (b - 1)) / 2;
}

// 64 rows per block; zeroes its slice of rowW/rowN; block 0 zeroes header.
__global__ __launch_bounds__(256) void prep_kernel(
    const float* __restrict__ emb, const int* __restrict__ labels,
    float2* __restrict__ lsq, unsigned short* __restrict__ ebf,
    float* __restrict__ rowW, float* __restrict__ rowN, float* __restrict__ hdr)
{
    int t = threadIdx.x;
    if (blockIdx.x == 0 && t < 8) hdr[t] = 0.f;   // posAcc, ctr, pad
    if (t < 64) {
        rowW[blockIdx.x * 64 + t] = 0.f;
        rowN[blockIdx.x * 64 + t] = 0.f;
    }
    int row = blockIdx.x * 64 + (t >> 2);
    int quad = t & 3;
    const float4* src = (const float4*)(emb + (size_t)row * D + quad * 32);
    ushort4* dst = (ushort4*)(ebf + (size_t)row * D + quad * 32);
    float s = 0.f;
#pragma unroll
    for (int i = 0; i < 8; ++i) {
        float4 v = src[i];
        s += v.x * v.x + v.y * v.y + v.z * v.z + v.w * v.w;
        ushort4 o;
        o.x = f2bf(v.x); o.y = f2bf(v.y); o.z = f2bf(v.z); o.w = f2bf(v.w);
        dst[i] = o;
    }
    s += __shfl_xor(s, 1, 4);
    s += __shfl_xor(s, 2, 4);
    if (quad == 0) lsq[row] = make_float2(s, (float)labels[row]);
}

// NOTE: no second launch_bounds arg — R6's (512,4) capped VGPRs at 64 and caused
// 125 MB/dispatch scratch spill. LDS (67 KB) already limits to 2 blocks/CU.
__global__ __launch_bounds__(512) void pair_kernel(
    const unsigned short* __restrict__ ebf, const float2* __restrict__ lsq,
    const int* __restrict__ labels,
    float* __restrict__ rowW, float* __restrict__ rowN,
    float* __restrict__ posAcc, unsigned int* __restrict__ ctr,
    float* __restrict__ out)
{
    __shared__ short As[128 * 128];
    __shared__ short Bs[128 * 128];
    __shared__ float2 lsqR[128];
    __shared__ float2 lsqC[128];
    __shared__ float wred[8];
    __shared__ float cw[NUM_CLASSES];
    __shared__ float cn[NUM_CLASSES];
    __shared__ int lastFlag;

    const int t = threadIdx.x;
    const int b = blockIdx.x;
    const int lane = t & 63;
    const int w = t >> 6;
    const int wy = w >> 2;     // 0..1 (row 64-half)
    const int wx = w & 3;      // 0..3 (col 32-quarter)
    const int m = lane & 15;
    const int q = lane >> 4;
    const int sw = m & 7;
    const uint4* src = (const uint4*)ebf;

    // contiguous tile range for this block (4 or 5 tiles)
    const int lo = (b * NTILE) / GRIDP;
    const int hi = ((b + 1) * NTILE) / GRIDP;

    // ---- decode first tile (by, bx), bx >= by ----
    int by = (int)((129.0f - sqrtf(16641.0f - 8.0f * (float)lo)) * 0.5f);
    if (by < 0) by = 0;
    if (by > NB - 1) by = NB - 1;
    while (by + 1 <= NB - 1 && tri_off(by + 1) <= lo) ++by;
    while (by > 0 && tri_off(by) > lo) --by;
    int bx = by + (lo - tri_off(by));

    // ---- prefetch first tile into registers ----
    uint4 va[4], vb[4];
    float2 pR, pC;
    {
        const int r0 = by * 128, c0 = bx * 128;
#pragma unroll
        for (int it = 0; it < 4; ++it) {
            int f = it * 512 + t;
            int r = f >> 4, g = f & 15;
            va[it] = src[(size_t)(r0 + r) * 16 + g];
            vb[it] = src[(size_t)(c0 + r) * 16 + g];
        }
        if (t < 128) pR = lsq[r0 + t];
        else if (t < 256) pC = lsq[c0 + (t - 128)];
    }

    float pos = 0.f;

#pragma unroll 1
    for (int tile = lo; tile < hi; ++tile) {
        const int cby = by, cbx = bx;
        const int r0 = cby * 128, c0 = cbx * 128;

        __syncthreads();   // previous tile's readers done
#pragma unroll
        for (int it = 0; it < 4; ++it) {
            int f = it * 512 + t;
            int r = f >> 4, g = f & 15;
            int slot = (g ^ (r & 7)) << 3;
            *(uint4*)(&As[r * 128 + slot]) = va[it];
            *(uint4*)(&Bs[r * 128 + slot]) = vb[it];
        }
        if (t < 128) lsqR[t] = pR;
        else if (t < 256) lsqC[t - 128] = pC;
        __syncthreads();

        // prefetch next tile while this one computes
        if (tile + 1 < hi) {
            if (bx + 1 <= NB - 1) { ++bx; } else { ++by; bx = by; }
            const int nr0 = by * 128, nc0 = bx * 128;
#pragma unroll
            for (int it = 0; it < 4; ++it) {
                int f = it * 512 + t;
                int r = f >> 4, g = f & 15;
                va[it] = src[(size_t)(nr0 + r) * 16 + g];
                vb[it] = src[(size_t)(nc0 + r) * 16 + g];
            }
            if (t < 128) pR = lsq[nr0 + t];
            else if (t < 256) pC = lsq[nc0 + (t - 128)];
        }

        // ---- MFMA ----
        f32x4 acc[4][2];
#pragma unroll
        for (int ii = 0; ii < 4; ++ii)
#pragma unroll
            for (int jj = 0; jj < 2; ++jj) acc[ii][jj] = (f32x4){0.f, 0.f, 0.f, 0.f};

#pragma unroll
        for (int kk = 0; kk < 4; ++kk) {
            int gs = ((kk * 4 + q) ^ sw) << 3;
            short8 a[4], bb[2];
#pragma unroll
            for (int rt = 0; rt < 4; ++rt)
                a[rt] = *(const short8*)(&As[(wy * 64 + rt * 16 + m) * 128 + gs]);
#pragma unroll
            for (int ct = 0; ct < 2; ++ct)
                bb[ct] = *(const short8*)(&Bs[(wx * 32 + ct * 16 + m) * 128 + gs]);
#pragma unroll
            for (int rt = 0; rt < 4; ++rt)
#pragma unroll
                for (int ct = 0; ct < 2; ++ct)
                    acc[rt][ct] = __builtin_amdgcn_mfma_f32_16x16x32_bf16(
                        a[rt], bb[ct], acc[rt][ct], 0, 0, 0);
        }

        // ---- branch-free hot epilogue; u = dist - POS_TH ----
        float scm[2], lc[2];
#pragma unroll
        for (int ct = 0; ct < 2; ++ct) {
            float2 v = lsqC[wx * 32 + ct * 16 + m];
            scm[ct] = v.x - POS_TH;
            lc[ct] = v.y;
        }

        float ptile = 0.f;
        float md = 1e30f;
#pragma unroll
        for (int rt = 0; rt < 4; ++rt) {
            float sr[4], lr[4];
#pragma unroll
            for (int reg = 0; reg < 4; ++reg) {
                float2 v = lsqR[wy * 64 + rt * 16 + q * 4 + reg];
                sr[reg] = v.x; lr[reg] = v.y;
            }
#pragma unroll
            for (int ct = 0; ct < 2; ++ct) {
                f32x4 A = acc[rt][ct];
#pragma unroll
                for (int reg = 0; reg < 4; ++reg) {
                    float u = fmaf(A[reg], -2.f, sr[reg]) + scm[ct];
                    md = fminf(md, u);
                    float rel = fmaxf(u, 0.f);
                    ptile += (lr[reg] == lc[ct]) ? rel : 0.f;
                }
            }
        }

        // cold path: exact negatives (diag blocks trigger detector, find none)
        if (__any(md < (ALPHAF - POS_TH))) {
            const bool offd = (cbx != cby);
#pragma unroll
            for (int rt = 0; rt < 4; ++rt) {
                float sr[4], lr[4];
#pragma unroll
                for (int reg = 0; reg < 4; ++reg) {
                    float2 v = lsqR[wy * 64 + rt * 16 + q * 4 + reg];
                    sr[reg] = v.x; lr[reg] = v.y;
                }
#pragma unroll
                for (int ct = 0; ct < 2; ++ct) {
                    f32x4 A = acc[rt][ct];
#pragma unroll
                    for (int reg = 0; reg < 4; ++reg) {
                        float u = fmaf(A[reg], -2.f, sr[reg]) + scm[ct];
                        if (lr[reg] != lc[ct] && u < (ALPHAF - POS_TH)) {
                            float gap = (ALPHAF - POS_TH) - u;
                            float wv = __expf(TF * gap);
                            int r = r0 + wy * 64 + rt * 16 + q * 4 + reg;
                            int c = c0 + wx * 32 + ct * 16 + m;
                            atomicAdd(&rowW[r], wv);
                            atomicAdd(&rowN[r], gap * wv);
                            if (offd) {
                                atomicAdd(&rowW[c], wv);
                                atomicAdd(&rowN[c], gap * wv);
                            }
                        }
                    }
                }
            }
        }

        pos += (cbx != cby) ? 2.f * ptile : ptile;
    }

    // ---- block-reduce pos -> one atomic per block ----
#pragma unroll
    for (int off = 1; off < 64; off <<= 1) pos += __shfl_xor(pos, off, 64);
    __syncthreads();
    if (lane == 0) wred[w] = pos;
    __syncthreads();
    if (t == 0) {
        float s = 0.f;
#pragma unroll
        for (int ii = 0; ii < 8; ++ii) s += wred[ii];
        atomicAdd(posAcc, s);
        __threadfence();
        unsigned prev = atomicAdd(ctr, 1u);
        lastFlag = (prev == GRIDP - 1) ? 1 : 0;
    }
    __syncthreads();

    // ---- last block: fused finalize (all cross-block data was atomic-written) ----
    if (lastFlag) {
        __threadfence();
        if (t < NUM_CLASSES) { cw[t] = 0.f; cn[t] = 0.f; }
        __syncthreads();
        for (int i = t; i < N; i += 512) {
            int c = labels[i];
            float rw = __hip_atomic_load(&rowW[i], __ATOMIC_RELAXED, __HIP_MEMORY_SCOPE_AGENT);
            float rn = __hip_atomic_load(&rowN[i], __ATOMIC_RELAXED, __HIP_MEMORY_SCOPE_AGENT);
            atomicAdd(&cw[c], rw);
            atomicAdd(&cn[c], rn);
        }
        __syncthreads();
        if (t < NUM_CLASSES) {
            float v = (cw[t] > 0.f) ? (cn[t] / cw[t]) : 0.f;
#pragma unroll
            for (int off = 1; off < 64; off <<= 1) v += __shfl_xor(v, off, 64);
            if (t == 0) {
                float pt = __hip_atomic_load(posAcc, __ATOMIC_RELAXED, __HIP_MEMORY_SCOPE_AGENT);
                out[0] = pt + v;
                out[1] = (float)N;
            }
        }
    }
}

extern "C" void kernel_launch(void* const* d_in, const int* in_sizes, int n_in,
                              void* d_out, int out_size, void* d_ws, size_t ws_size,
                              hipStream_t stream) {
    const float* emb = (const float*)d_in[0];
    const int* labels = (const int*)d_in[1];
    float* out = (float*)d_out;
    float* ws = (float*)d_ws;

    float* posAcc = ws;
    unsigned int* ctr = (unsigned int*)(ws + 1);
    float* rowW = ws + 8;
    float* rowN = ws + 8 + N;
    float2* lsq = (float2*)(ws + 8 + 2 * N);
    unsigned short* ebf = (unsigned short*)(ws + 8 + 4 * N);

    prep_kernel<<<dim3(N / 64), dim3(256), 0, stream>>>(emb, labels, lsq, ebf, rowW, rowN, ws);

    pair_kernel<<<dim3(GRIDP), dim3(512), 0, stream>>>(ebf, lsq, labels, rowW, rowN,
                                                       posAcc, ctr, out);
}

// Round 8
// 108.437 us; speedup vs baseline: 1.4254x; 1.4254x over previous
//
#include <hip/hip_runtime.h>
#include <math.h>

#define N 8192
#define D 128
#define NUM_CLASSES 64
#define POS_TH 0.8f   // ALPHA - MARGIN
#define ALPHAF 1.2f
#define TF 10.0f
#define NB 64               // N / 128 tile grid dim
#define NTILE 2080          // NB*(NB+1)/2 upper-tri tiles
#define GRIDP 512           // 2 blocks/CU x 256 CU; contiguous 4-5 tile ranges

typedef __attribute__((ext_vector_type(8))) short short8;   // 8 x bf16
typedef __attribute__((ext_vector_type(4))) float f32x4;
typedef const __attribute__((address_space(1))) unsigned int guint;
typedef __attribute__((address_space(3))) unsigned int luint;

// ws layout (floats):
//  [0]       posAcc   (zeroed by prep)
//  [1]       ctr      (uint, zeroed by prep)
//  [2..8)    pad
//  [8..8+N)      rowW (zeroed by prep)
//  [8+N..8+2N)   rowN
//  [8+2N..8+4N)  lsq  (float2 {sq, label})
//  [8+4N.. )     ebfT (N*D bf16 in tile-granule layout), 16B-aligned
//
// ebfT layout (uint4 units): band = row>>7 (64 bands), granule g in [0,16)
// (8 bf16 = 16B each), r = row&127:  ebfT4[band*2048 + g*128 + r].
// A 128x128 tile = ebfT4[band*2048 .. +2048) -- contiguous 32 KB.

static __device__ __forceinline__ unsigned short f2bf(float x) {
    unsigned u = __float_as_uint(x);
    u = u + 0x7fffu + ((u >> 16) & 1u);   // RNE
    return (unsigned short)(u >> 16);
}

static __device__ __forceinline__ unsigned pack2(float a, float b) {
    return (unsigned)f2bf(a) | ((unsigned)f2bf(b) << 16);
}

static __device__ __forceinline__ int tri_off(int b) {  // tiles before row b
    return b * NB - (b * (b - 1)) / 2;
}

// 64 rows per block; writes ebfT in tile-granule layout; zeroes rowW/rowN slice.
__global__ __launch_bounds__(256) void prep_kernel(
    const float* __restrict__ emb, const int* __restrict__ labels,
    float2* __restrict__ lsq, uint4* __restrict__ ebfT4,
    float* __restrict__ rowW, float* __restrict__ rowN, float* __restrict__ hdr)
{
    int t = threadIdx.x;
    if (blockIdx.x == 0 && t < 8) hdr[t] = 0.f;   // posAcc, ctr, pad
    if (t < 64) {
        rowW[blockIdx.x * 64 + t] = 0.f;
        rowN[blockIdx.x * 64 + t] = 0.f;
    }
    int row = blockIdx.x * 64 + (t >> 2);
    int quad = t & 3;
    const float4* src = (const float4*)(emb + (size_t)row * D + quad * 32);
    const int band = row >> 7, rl = row & 127;
    float s = 0.f;
#pragma unroll
    for (int i = 0; i < 4; ++i) {           // granule g = quad*4 + i (8 bf16 each)
        float4 v0 = src[i * 2];
        float4 v1 = src[i * 2 + 1];
        s += v0.x * v0.x + v0.y * v0.y + v0.z * v0.z + v0.w * v0.w;
        s += v1.x * v1.x + v1.y * v1.y + v1.z * v1.z + v1.w * v1.w;
        uint4 o;
        o.x = pack2(v0.x, v0.y); o.y = pack2(v0.z, v0.w);
        o.z = pack2(v1.x, v1.y); o.w = pack2(v1.z, v1.w);
        ebfT4[(size_t)band * 2048 + (quad * 4 + i) * 128 + rl] = o;
    }
    s += __shfl_xor(s, 1, 4);
    s += __shfl_xor(s, 2, 4);
    if (quad == 0) lsq[row] = make_float2(s, (float)labels[row]);
}

__global__ __launch_bounds__(512) void pair_kernel(
    const uint4* __restrict__ ebfT4, const float2* __restrict__ lsq,
    const int* __restrict__ labels,
    float* __restrict__ rowW, float* __restrict__ rowN,
    float* __restrict__ posAcc, unsigned int* __restrict__ ctr,
    float* __restrict__ out)
{
    __shared__ uint4 As4[2048];     // 32 KB: tile image, [g*128 + r]
    __shared__ uint4 Bs4[2048];
    __shared__ float2 lsqR[128];
    __shared__ float2 lsqC[128];
    __shared__ float wred[8];
    __shared__ float cw[NUM_CLASSES];
    __shared__ float cn[NUM_CLASSES];
    __shared__ int lastFlag;

    const int t = threadIdx.x;
    const int b = blockIdx.x;
    const int lane = t & 63;
    const int w = t >> 6;
    const int wy = w >> 2;     // 0..1 (row 64-half)
    const int wx = w & 3;      // 0..3 (col 32-quarter)
    const int m = lane & 15;
    const int q = lane >> 4;
    const short* As = (const short*)As4;
    const short* Bs = (const short*)Bs4;

    // contiguous tile range for this block (4 or 5 tiles)
    const int lo = (b * NTILE) / GRIDP;
    const int hi = ((b + 1) * NTILE) / GRIDP;

    // decode first tile (by, bx), bx >= by
    int by = (int)((129.0f - sqrtf(16641.0f - 8.0f * (float)lo)) * 0.5f);
    if (by < 0) by = 0;
    if (by > NB - 1) by = NB - 1;
    while (by + 1 <= NB - 1 && tri_off(by + 1) <= lo) ++by;
    while (by > 0 && tri_off(by) > lo) --by;
    int bx = by + (lo - tri_off(by));

    float pos = 0.f;

#pragma unroll 1
    for (int tile = lo; tile < hi; ++tile) {
        const int r0 = by * 128, c0 = bx * 128;

        __syncthreads();   // previous tile's readers done
        // ---- async global->LDS staging: pure memcpy of two 32 KB bands ----
        {
            const uint4* gA = ebfT4 + (size_t)by * 2048;
            const uint4* gB = ebfT4 + (size_t)bx * 2048;
#pragma unroll
            for (int j = 0; j < 4; ++j) {
                int chunk = w * 4 + j;                 // 64 uint4 per wave-call
                __builtin_amdgcn_global_load_lds(
                    (guint*)(gA + chunk * 64 + lane),
                    (luint*)(&As4[chunk * 64]), 16, 0, 0);
                __builtin_amdgcn_global_load_lds(
                    (guint*)(gB + chunk * 64 + lane),
                    (luint*)(&Bs4[chunk * 64]), 16, 0, 0);
            }
        }
        if (t < 128) lsqR[t] = lsq[r0 + t];
        else if (t < 256) lsqC[t - 128] = lsq[c0 + (t - 128)];
        __syncthreads();   // drains vmcnt (DMA) + lgkm

        // ---- MFMA ----
        f32x4 acc[4][2];
#pragma unroll
        for (int ii = 0; ii < 4; ++ii)
#pragma unroll
            for (int jj = 0; jj < 2; ++jj) acc[ii][jj] = (f32x4){0.f, 0.f, 0.f, 0.f};

#pragma unroll
        for (int kk = 0; kk < 4; ++kk) {
            const int g = kk * 4 + q;                  // granule = k-range [g*8, g*8+8)
            short8 a[4], bb[2];
#pragma unroll
            for (int rt = 0; rt < 4; ++rt)
                a[rt] = *(const short8*)(&As[(g * 128 + wy * 64 + rt * 16 + m) * 8]);
#pragma unroll
            for (int ct = 0; ct < 2; ++ct)
                bb[ct] = *(const short8*)(&Bs[(g * 128 + wx * 32 + ct * 16 + m) * 8]);
#pragma unroll
            for (int rt = 0; rt < 4; ++rt)
#pragma unroll
                for (int ct = 0; ct < 2; ++ct)
                    acc[rt][ct] = __builtin_amdgcn_mfma_f32_16x16x32_bf16(
                        a[rt], bb[ct], acc[rt][ct], 0, 0, 0);
        }

        // ---- branch-free hot epilogue; u = dist - POS_TH ----
        float scm[2], lc[2];
#pragma unroll
        for (int ct = 0; ct < 2; ++ct) {
            float2 v = lsqC[wx * 32 + ct * 16 + m];
            scm[ct] = v.x - POS_TH;
            lc[ct] = v.y;
        }

        float ptile = 0.f;
        float md = 1e30f;
#pragma unroll
        for (int rt = 0; rt < 4; ++rt) {
            float sr[4], lr[4];
#pragma unroll
            for (int reg = 0; reg < 4; ++reg) {
                float2 v = lsqR[wy * 64 + rt * 16 + q * 4 + reg];
                sr[reg] = v.x; lr[reg] = v.y;
            }
#pragma unroll
            for (int ct = 0; ct < 2; ++ct) {
                f32x4 A = acc[rt][ct];
#pragma unroll
                for (int reg = 0; reg < 4; ++reg) {
                    float u = fmaf(A[reg], -2.f, sr[reg]) + scm[ct];
                    md = fminf(md, u);
                    float rel = fmaxf(u, 0.f);
                    ptile += (lr[reg] == lc[ct]) ? rel : 0.f;
                }
            }
        }

        // cold path: exact negatives (diag blocks trigger detector, find none)
        if (__any(md < (ALPHAF - POS_TH))) {
            const bool offd = (bx != by);
#pragma unroll
            for (int rt = 0; rt < 4; ++rt) {
                float sr[4], lr[4];
#pragma unroll
                for (int reg = 0; reg < 4; ++reg) {
                    float2 v = lsqR[wy * 64 + rt * 16 + q * 4 + reg];
                    sr[reg] = v.x; lr[reg] = v.y;
                }
#pragma unroll
                for (int ct = 0; ct < 2; ++ct) {
                    f32x4 A = acc[rt][ct];
#pragma unroll
                    for (int reg = 0; reg < 4; ++reg) {
                        float u = fmaf(A[reg], -2.f, sr[reg]) + scm[ct];
                        if (lr[reg] != lc[ct] && u < (ALPHAF - POS_TH)) {
                            float gap = (ALPHAF - POS_TH) - u;
                            float wv = __expf(TF * gap);
                            int r = r0 + wy * 64 + rt * 16 + q * 4 + reg;
                            int c = c0 + wx * 32 + ct * 16 + m;
                            atomicAdd(&rowW[r], wv);
                            atomicAdd(&rowN[r], gap * wv);
                            if (offd) {
                                atomicAdd(&rowW[c], wv);
                                atomicAdd(&rowN[c], gap * wv);
                            }
                        }
                    }
                }
            }
        }

        pos += (bx != by) ? 2.f * ptile : ptile;

        // advance to next upper-tri tile
        if (bx + 1 <= NB - 1) { ++bx; } else { ++by; bx = by; }
    }

    // ---- block-reduce pos -> one atomic per block ----
#pragma unroll
    for (int off = 1; off < 64; off <<= 1) pos += __shfl_xor(pos, off, 64);
    __syncthreads();
    if (lane == 0) wred[w] = pos;
    __syncthreads();
    if (t == 0) {
        float s = 0.f;
#pragma unroll
        for (int ii = 0; ii < 8; ++ii) s += wred[ii];
        atomicAdd(posAcc, s);
        __threadfence();
        unsigned prev = atomicAdd(ctr, 1u);
        lastFlag = (prev == GRIDP - 1) ? 1 : 0;
    }
    __syncthreads();

    // ---- last block: fused finalize (all cross-block data was atomic-written) ----
    if (lastFlag) {
        __threadfence();
        if (t < NUM_CLASSES) { cw[t] = 0.f; cn[t] = 0.f; }
        __syncthreads();
        for (int i = t; i < N; i += 512) {
            int c = labels[i];
            float rw = __hip_atomic_load(&rowW[i], __ATOMIC_RELAXED, __HIP_MEMORY_SCOPE_AGENT);
            float rn = __hip_atomic_load(&rowN[i], __ATOMIC_RELAXED, __HIP_MEMORY_SCOPE_AGENT);
            atomicAdd(&cw[c], rw);
            atomicAdd(&cn[c], rn);
        }
        __syncthreads();
        if (t < NUM_CLASSES) {
            float v = (cw[t] > 0.f) ? (cn[t] / cw[t]) : 0.f;
#pragma unroll
            for (int off = 1; off < 64; off <<= 1) v += __shfl_xor(v, off, 64);
            if (t == 0) {
                float pt = __hip_atomic_load(posAcc, __ATOMIC_RELAXED, __HIP_MEMORY_SCOPE_AGENT);
                out[0] = pt + v;
                out[1] = (float)N;
            }
        }
    }
}

extern "C" void kernel_launch(void* const* d_in, const int* in_sizes, int n_in,
                              void* d_out, int out_size, void* d_ws, size_t ws_size,
                              hipStream_t stream) {
    const float* emb = (const float*)d_in[0];
    const int* labels = (const int*)d_in[1];
    float* out = (float*)d_out;
    float* ws = (float*)d_ws;

    float* posAcc = ws;
    unsigned int* ctr = (unsigned int*)(ws + 1);
    float* rowW = ws + 8;
    float* rowN = ws + 8 + N;
    float2* lsq = (float2*)(ws + 8 + 2 * N);
    uint4* ebfT4 = (uint4*)(ws + 8 + 4 * N);   // offset (8+4N)*4 B, 16B-aligned

    prep_kernel<<<dim3(N / 64), dim3(256), 0, stream>>>(emb, labels, lsq, ebfT4, rowW, rowN, ws);

    pair_kernel<<<dim3(GRIDP), dim3(512), 0, stream>>>(ebfT4, lsq, labels, rowW, rowN,
                                                       posAcc, ctr, out);
}

// Round 9
// 105.604 us; speedup vs baseline: 1.4637x; 1.0268x over previous
//
#include <hip/hip_runtime.h>
#include <math.h>

#define N 8192
#define D 128
#define NUM_CLASSES 64
#define POS_TH 0.8f   // ALPHA - MARGIN
#define ALPHAF 1.2f
#define TF 10.0f
#define NB 64               // N / 128 tile grid dim
#define NTILE 2080          // NB*(NB+1)/2 upper-tri tiles
#define GRIDP 256           // 1 block/CU (128 KB LDS dbuf); ~8 tiles per block

typedef __attribute__((ext_vector_type(8))) short short8;   // 8 x bf16
typedef __attribute__((ext_vector_type(4))) float f32x4;
typedef const __attribute__((address_space(1))) unsigned int guint;
typedef __attribute__((address_space(3))) unsigned int luint;

// ws layout (floats):
//  [0] posAcc | [1] ctr | [2..8) pad
//  [8..8+N) rowW | [8+N..8+2N) rowN | [8+2N..8+4N) lsq (float2 {sq,label})
//  [8+4N..) ebfT: band-granule layout, uint4 units:
//    band = row>>7, granule g in [0,16), r = row&127 -> ebfT4[band*2048 + g*128 + r]
//    => one 128x128 tile = contiguous 32 KB (pure memcpy for global_load_lds)

static __device__ __forceinline__ unsigned short f2bf(float x) {
    unsigned u = __float_as_uint(x);
    u = u + 0x7fffu + ((u >> 16) & 1u);   // RNE
    return (unsigned short)(u >> 16);
}

static __device__ __forceinline__ unsigned pack2(float a, float b) {
    return (unsigned)f2bf(a) | ((unsigned)f2bf(b) << 16);
}

static __device__ __forceinline__ int tri_off(int b) {  // tiles before row b
    return b * NB - (b * (b - 1)) / 2;
}

__global__ __launch_bounds__(256) void prep_kernel(
    const float* __restrict__ emb, const int* __restrict__ labels,
    float2* __restrict__ lsq, uint4* __restrict__ ebfT4,
    float* __restrict__ rowW, float* __restrict__ rowN, float* __restrict__ hdr)
{
    int t = threadIdx.x;
    if (blockIdx.x == 0 && t < 8) hdr[t] = 0.f;   // posAcc, ctr, pad
    if (t < 64) {
        rowW[blockIdx.x * 64 + t] = 0.f;
        rowN[blockIdx.x * 64 + t] = 0.f;
    }
    int row = blockIdx.x * 64 + (t >> 2);
    int quad = t & 3;
    const float4* src = (const float4*)(emb + (size_t)row * D + quad * 32);
    const int band = row >> 7, rl = row & 127;
    float s = 0.f;
#pragma unroll
    for (int i = 0; i < 4; ++i) {           // granule g = quad*4 + i (8 bf16 each)
        float4 v0 = src[i * 2];
        float4 v1 = src[i * 2 + 1];
        s += v0.x * v0.x + v0.y * v0.y + v0.z * v0.z + v0.w * v0.w;
        s += v1.x * v1.x + v1.y * v1.y + v1.z * v1.z + v1.w * v1.w;
        uint4 o;
        o.x = pack2(v0.x, v0.y); o.y = pack2(v0.z, v0.w);
        o.z = pack2(v1.x, v1.y); o.w = pack2(v1.z, v1.w);
        ebfT4[(size_t)band * 2048 + (quad * 4 + i) * 128 + rl] = o;
    }
    s += __shfl_xor(s, 1, 4);
    s += __shfl_xor(s, 2, 4);
    if (quad == 0) lsq[row] = make_float2(s, (float)labels[row]);
}

__global__ __launch_bounds__(512) void pair_kernel(
    const uint4* __restrict__ ebfT4, const float2* __restrict__ lsq,
    const int* __restrict__ labels,
    float* __restrict__ rowW, float* __restrict__ rowN,
    float* __restrict__ posAcc, unsigned int* __restrict__ ctr,
    float* __restrict__ out)
{
    __shared__ uint4 As4[2][2048];     // 2 x 32 KB double-buffered A tile
    __shared__ uint4 Bs4[2][2048];     // 2 x 32 KB double-buffered B tile
    __shared__ float2 lsqRS[2][128];
    __shared__ float2 lsqCS[2][128];
    __shared__ float wred[8];
    __shared__ float cw[NUM_CLASSES];
    __shared__ float cn[NUM_CLASSES];
    __shared__ int lastFlag;

    const int t = threadIdx.x;
    const int b = blockIdx.x;
    const int lane = t & 63;
    const int w = t >> 6;
    const int wy = w >> 2;     // 0..1 (row 64-half)
    const int wx = w & 3;      // 0..3 (col 32-quarter)
    const int m = lane & 15;
    const int q = lane >> 4;

    const int lo = (b * NTILE) / GRIDP;
    const int hi = ((b + 1) * NTILE) / GRIDP;

    // decode first tile (by, bx), bx >= by
    int cby = (int)((129.0f - sqrtf(16641.0f - 8.0f * (float)lo)) * 0.5f);
    if (cby < 0) cby = 0;
    if (cby > NB - 1) cby = NB - 1;
    while (cby + 1 <= NB - 1 && tri_off(cby + 1) <= lo) ++cby;
    while (cby > 0 && tri_off(cby) > lo) --cby;
    int cbx = cby + (lo - tri_off(cby));

    // ---- prologue: stage tile lo into buffer 0 ----
    {
        const uint4* gA = ebfT4 + (size_t)cby * 2048;
        const uint4* gB = ebfT4 + (size_t)cbx * 2048;
#pragma unroll
        for (int j = 0; j < 4; ++j) {
            int chunk = w * 4 + j;
            __builtin_amdgcn_global_load_lds((guint*)(gA + chunk * 64 + lane),
                                             (luint*)(&As4[0][chunk * 64]), 16, 0, 0);
            __builtin_amdgcn_global_load_lds((guint*)(gB + chunk * 64 + lane),
                                             (luint*)(&Bs4[0][chunk * 64]), 16, 0, 0);
        }
        if (t < 128) lsqRS[0][t] = lsq[cby * 128 + t];
        else if (t < 256) lsqCS[0][t - 128] = lsq[cbx * 128 + (t - 128)];
    }
    __syncthreads();   // drain prologue DMA + lsq

    float pos = 0.f;
    int cur = 0;

#pragma unroll 1
    for (int tile = lo; tile < hi; ++tile) {
        const int r0 = cby * 128, c0 = cbx * 128;
        const bool havenext = (tile + 1 < hi);
        int nby = cby, nbx = cbx;
        float2 vR, vC;

        // ---- issue next tile's DMA into the other buffer (latency hidden by compute) ----
        if (havenext) {
            if (nbx + 1 <= NB - 1) { ++nbx; } else { ++nby; nbx = nby; }
            const uint4* gA = ebfT4 + (size_t)nby * 2048;
            const uint4* gB = ebfT4 + (size_t)nbx * 2048;
            uint4* dA = As4[cur ^ 1];
            uint4* dB = Bs4[cur ^ 1];
#pragma unroll
            for (int j = 0; j < 4; ++j) {
                int chunk = w * 4 + j;
                __builtin_amdgcn_global_load_lds((guint*)(gA + chunk * 64 + lane),
                                                 (luint*)(dA + chunk * 64), 16, 0, 0);
                __builtin_amdgcn_global_load_lds((guint*)(gB + chunk * 64 + lane),
                                                 (luint*)(dB + chunk * 64), 16, 0, 0);
            }
            if (t < 128) vR = lsq[nby * 128 + t];
            else if (t < 256) vC = lsq[nbx * 128 + (t - 128)];
        }

        // ---- MFMA from current buffer ----
        const short* As = (const short*)As4[cur];
        const short* Bs = (const short*)Bs4[cur];
        f32x4 acc[4][2];
#pragma unroll
        for (int ii = 0; ii < 4; ++ii)
#pragma unroll
            for (int jj = 0; jj < 2; ++jj) acc[ii][jj] = (f32x4){0.f, 0.f, 0.f, 0.f};

#pragma unroll
        for (int kk = 0; kk < 4; ++kk) {
            const int g = kk * 4 + q;
            short8 a[4], bb[2];
#pragma unroll
            for (int rt = 0; rt < 4; ++rt)
                a[rt] = *(const short8*)(&As[(g * 128 + wy * 64 + rt * 16 + m) * 8]);
#pragma unroll
            for (int ct = 0; ct < 2; ++ct)
                bb[ct] = *(const short8*)(&Bs[(g * 128 + wx * 32 + ct * 16 + m) * 8]);
#pragma unroll
            for (int rt = 0; rt < 4; ++rt)
#pragma unroll
                for (int ct = 0; ct < 2; ++ct)
                    acc[rt][ct] = __builtin_amdgcn_mfma_f32_16x16x32_bf16(
                        a[rt], bb[ct], acc[rt][ct], 0, 0, 0);
        }

        // ---- branch-free hot epilogue; u = dist - POS_TH ----
        float scm[2], lc[2];
#pragma unroll
        for (int ct = 0; ct < 2; ++ct) {
            float2 v = lsqCS[cur][wx * 32 + ct * 16 + m];
            scm[ct] = v.x - POS_TH;
            lc[ct] = v.y;
        }

        float ptile = 0.f;
        float md = 1e30f;
#pragma unroll
        for (int rt = 0; rt < 4; ++rt) {
            float sr[4], lr[4];
#pragma unroll
            for (int reg = 0; reg < 4; ++reg) {
                float2 v = lsqRS[cur][wy * 64 + rt * 16 + q * 4 + reg];
                sr[reg] = v.x; lr[reg] = v.y;
            }
#pragma unroll
            for (int ct = 0; ct < 2; ++ct) {
                f32x4 A = acc[rt][ct];
#pragma unroll
                for (int reg = 0; reg < 4; ++reg) {
                    float u = fmaf(A[reg], -2.f, sr[reg]) + scm[ct];
                    md = fminf(md, u);
                    float rel = fmaxf(u, 0.f);
                    ptile += (lr[reg] == lc[ct]) ? rel : 0.f;
                }
            }
        }

        // cold path: exact negatives (diag blocks trigger detector, find none)
        if (__any(md < (ALPHAF - POS_TH))) {
            const bool offd = (cbx != cby);
#pragma unroll
            for (int rt = 0; rt < 4; ++rt) {
                float sr[4], lr[4];
#pragma unroll
                for (int reg = 0; reg < 4; ++reg) {
                    float2 v = lsqRS[cur][wy * 64 + rt * 16 + q * 4 + reg];
                    sr[reg] = v.x; lr[reg] = v.y;
                }
#pragma unroll
                for (int ct = 0; ct < 2; ++ct) {
                    f32x4 A = acc[rt][ct];
#pragma unroll
                    for (int reg = 0; reg < 4; ++reg) {
                        float u = fmaf(A[reg], -2.f, sr[reg]) + scm[ct];
                        if (lr[reg] != lc[ct] && u < (ALPHAF - POS_TH)) {
                            float gap = (ALPHAF - POS_TH) - u;
                            float wv = __expf(TF * gap);
                            int r = r0 + wy * 64 + rt * 16 + q * 4 + reg;
                            int c = c0 + wx * 32 + ct * 16 + m;
                            atomicAdd(&rowW[r], wv);
                            atomicAdd(&rowN[r], gap * wv);
                            if (offd) {
                                atomicAdd(&rowW[c], wv);
                                atomicAdd(&rowN[c], gap * wv);
                            }
                        }
                    }
                }
            }
        }

        pos += (cbx != cby) ? 2.f * ptile : ptile;

        // stash next tile's lsq into the other LDS buffer (load long since landed)
        if (havenext) {
            if (t < 128) lsqRS[cur ^ 1][t] = vR;
            else if (t < 256) lsqCS[cur ^ 1][t - 128] = vC;
        }

        __syncthreads();   // drains next-tile DMA (already complete) + LDS writes
        cur ^= 1;
        cby = nby; cbx = nbx;
    }

    // ---- block-reduce pos -> one atomic per block ----
#pragma unroll
    for (int off = 1; off < 64; off <<= 1) pos += __shfl_xor(pos, off, 64);
    __syncthreads();
    if (lane == 0) wred[w] = pos;
    __syncthreads();
    if (t == 0) {
        float s = 0.f;
#pragma unroll
        for (int ii = 0; ii < 8; ++ii) s += wred[ii];
        atomicAdd(posAcc, s);
        __threadfence();
        unsigned prev = atomicAdd(ctr, 1u);
        lastFlag = (prev == GRIDP - 1) ? 1 : 0;
    }
    __syncthreads();

    // ---- last block: fused finalize ----
    if (lastFlag) {
        __threadfence();
        if (t < NUM_CLASSES) { cw[t] = 0.f; cn[t] = 0.f; }
        __syncthreads();
        for (int i = t; i < N; i += 512) {
            int c = labels[i];
            float rw = __hip_atomic_load(&rowW[i], __ATOMIC_RELAXED, __HIP_MEMORY_SCOPE_AGENT);
            float rn = __hip_atomic_load(&rowN[i], __ATOMIC_RELAXED, __HIP_MEMORY_SCOPE_AGENT);
            atomicAdd(&cw[c], rw);
            atomicAdd(&cn[c], rn);
        }
        __syncthreads();
        if (t < NUM_CLASSES) {
            float v = (cw[t] > 0.f) ? (cn[t] / cw[t]) : 0.f;
#pragma unroll
            for (int off = 1; off < 64; off <<= 1) v += __shfl_xor(v, off, 64);
            if (t == 0) {
                float pt = __hip_atomic_load(posAcc, __ATOMIC_RELAXED, __HIP_MEMORY_SCOPE_AGENT);
                out[0] = pt + v;
                out[1] = (float)N;
            }
        }
    }
}

extern "C" void kernel_launch(void* const* d_in, const int* in_sizes, int n_in,
                              void* d_out, int out_size, void* d_ws, size_t ws_size,
                              hipStream_t stream) {
    const float* emb = (const float*)d_in[0];
    const int* labels = (const int*)d_in[1];
    float* out = (float*)d_out;
    float* ws = (float*)d_ws;

    float* posAcc = ws;
    unsigned int* ctr = (unsigned int*)(ws + 1);
    float* rowW = ws + 8;
    float* rowN = ws + 8 + N;
    float2* lsq = (float2*)(ws + 8 + 2 * N);
    uint4* ebfT4 = (uint4*)(ws + 8 + 4 * N);   // 16B-aligned

    prep_kernel<<<dim3(N / 64), dim3(256), 0, stream>>>(emb, labels, lsq, ebfT4, rowW, rowN, ws);

    pair_kernel<<<dim3(GRIDP), dim3(512), 0, stream>>>(ebfT4, lsq, labels, rowW, rowN,
                                                       posAcc, ctr, out);
}

// Round 10
// 104.922 us; speedup vs baseline: 1.4732x; 1.0065x over previous
//
#include <hip/hip_runtime.h>
#include <math.h>

#define N 8192
#define D 128
#define NUM_CLASSES 64
#define POS_TH 0.8f   // ALPHA - MARGIN
#define ALPHAF 1.2f
#define TF 10.0f
#define NB 64               // N / 128 tile grid dim
#define NTILE 2080          // NB*(NB+1)/2 upper-tri tiles
#define GRIDP 256           // 1 block/CU; ~8 row-contiguous tiles per block

typedef __attribute__((ext_vector_type(8))) short short8;   // 8 x bf16
typedef __attribute__((ext_vector_type(4))) float f32x4;
typedef const __attribute__((address_space(1))) unsigned int guint;
typedef __attribute__((address_space(3))) unsigned int luint;

// ws layout (floats):
//  [0] posAcc | [1] ctr | [2..8) pad
//  [8..8+N) rowW | [8+N..8+2N) rowN | [8+2N..8+4N) lsq (float2 {sq,label})
//  [8+4N..) ebfT: band-granule layout, uint4 units:
//    band = row>>7, granule g in [0,16), r = row&127 -> ebfT4[band*2048 + g*128 + r]
//    => one 128x128 tile = contiguous 32 KB (pure memcpy for global_load_lds)

static __device__ __forceinline__ unsigned short f2bf(float x) {
    unsigned u = __float_as_uint(x);
    u = u + 0x7fffu + ((u >> 16) & 1u);   // RNE
    return (unsigned short)(u >> 16);
}

static __device__ __forceinline__ unsigned pack2(float a, float b) {
    return (unsigned)f2bf(a) | ((unsigned)f2bf(b) << 16);
}

static __device__ __forceinline__ int tri_off(int b) {  // tiles before row b
    return b * NB - (b * (b - 1)) / 2;
}

__global__ __launch_bounds__(256) void prep_kernel(
    const float* __restrict__ emb, const int* __restrict__ labels,
    float2* __restrict__ lsq, uint4* __restrict__ ebfT4,
    float* __restrict__ rowW, float* __restrict__ rowN, float* __restrict__ hdr)
{
    int t = threadIdx.x;
    if (blockIdx.x == 0 && t < 8) hdr[t] = 0.f;   // posAcc, ctr, pad
    if (t < 64) {
        rowW[blockIdx.x * 64 + t] = 0.f;
        rowN[blockIdx.x * 64 + t] = 0.f;
    }
    int row = blockIdx.x * 64 + (t >> 2);
    int quad = t & 3;
    const float4* src = (const float4*)(emb + (size_t)row * D + quad * 32);
    const int band = row >> 7, rl = row & 127;
    float s = 0.f;
#pragma unroll
    for (int i = 0; i < 4; ++i) {           // granule g = quad*4 + i (8 bf16 each)
        float4 v0 = src[i * 2];
        float4 v1 = src[i * 2 + 1];
        s += v0.x * v0.x + v0.y * v0.y + v0.z * v0.z + v0.w * v0.w;
        s += v1.x * v1.x + v1.y * v1.y + v1.z * v1.z + v1.w * v1.w;
        uint4 o;
        o.x = pack2(v0.x, v0.y); o.y = pack2(v0.z, v0.w);
        o.z = pack2(v1.x, v1.y); o.w = pack2(v1.z, v1.w);
        ebfT4[(size_t)band * 2048 + (quad * 4 + i) * 128 + rl] = o;
    }
    s += __shfl_xor(s, 1, 4);
    s += __shfl_xor(s, 2, 4);
    if (quad == 0) lsq[row] = make_float2(s, (float)labels[row]);
}

__global__ __launch_bounds__(512) void pair_kernel(
    const uint4* __restrict__ ebfT4, const float2* __restrict__ lsq,
    const int* __restrict__ labels,
    float* __restrict__ rowW, float* __restrict__ rowN,
    float* __restrict__ posAcc, unsigned int* __restrict__ ctr,
    float* __restrict__ out)
{
    __shared__ uint4 As4[2048];        // 32 KB A band — cached across same-row tiles
    __shared__ uint4 Bs4[2][2048];     // 2 x 32 KB double-buffered B tile
    __shared__ float2 lsqRS[128];
    __shared__ float2 lsqCS[2][128];
    __shared__ float wred[8];
    __shared__ float cw[NUM_CLASSES];
    __shared__ float cn[NUM_CLASSES];
    __shared__ int lastFlag;

    const int t = threadIdx.x;
    const int b = blockIdx.x;
    const int lane = t & 63;
    const int w = t >> 6;
    const int wy = w >> 2;     // 0..1 (row 64-half)
    const int wx = w & 3;      // 0..3 (col 32-quarter)
    const int m = lane & 15;
    const int q = lane >> 4;

    const int lo = (b * NTILE) / GRIDP;
    const int hi = ((b + 1) * NTILE) / GRIDP;

    // decode first tile (by, bx), bx >= by
    int cby = (int)((129.0f - sqrtf(16641.0f - 8.0f * (float)lo)) * 0.5f);
    if (cby < 0) cby = 0;
    if (cby > NB - 1) cby = NB - 1;
    while (cby + 1 <= NB - 1 && tri_off(cby + 1) <= lo) ++cby;
    while (cby > 0 && tri_off(cby) > lo) --cby;
    int cbx = cby + (lo - tri_off(cby));

    // ---- prologue: stage A band + first B tile into buffer 0 ----
    {
        const uint4* gA = ebfT4 + (size_t)cby * 2048;
        const uint4* gB = ebfT4 + (size_t)cbx * 2048;
#pragma unroll
        for (int j = 0; j < 4; ++j) {
            int chunk = w * 4 + j;
            __builtin_amdgcn_global_load_lds((guint*)(gA + chunk * 64 + lane),
                                             (luint*)(&As4[chunk * 64]), 16, 0, 0);
            __builtin_amdgcn_global_load_lds((guint*)(gB + chunk * 64 + lane),
                                             (luint*)(&Bs4[0][chunk * 64]), 16, 0, 0);
        }
        if (t < 128) lsqRS[t] = lsq[cby * 128 + t];
        else if (t < 256) lsqCS[0][t - 128] = lsq[cbx * 128 + (t - 128)];
    }
    __syncthreads();

    float pos = 0.f;
    int cur = 0;

#pragma unroll 1
    for (int tile = lo; tile < hi; ++tile) {
        const int r0 = cby * 128, c0 = cbx * 128;
        const bool havenext = (tile + 1 < hi);
        int nby = cby, nbx = cbx;
        bool samerow = false;
        float2 vC;

        // same-row prefetch: B only (A band stays resident)
        if (havenext) {
            if (nbx + 1 <= NB - 1) { ++nbx; } else { ++nby; nbx = nby; }
            samerow = (nby == cby);
            if (samerow) {
                const uint4* gB = ebfT4 + (size_t)nbx * 2048;
                uint4* dB = Bs4[cur ^ 1];
#pragma unroll
                for (int j = 0; j < 4; ++j) {
                    int chunk = w * 4 + j;
                    __builtin_amdgcn_global_load_lds((guint*)(gB + chunk * 64 + lane),
                                                     (luint*)(dB + chunk * 64), 16, 0, 0);
                }
                if (t >= 128 && t < 256) vC = lsq[nbx * 128 + (t - 128)];
            }
        }

        // ---- MFMA from A (cached) and B[cur] ----
        const short* As = (const short*)As4;
        const short* Bs = (const short*)Bs4[cur];
        f32x4 acc[4][2];
#pragma unroll
        for (int ii = 0; ii < 4; ++ii)
#pragma unroll
            for (int jj = 0; jj < 2; ++jj) acc[ii][jj] = (f32x4){0.f, 0.f, 0.f, 0.f};

#pragma unroll
        for (int kk = 0; kk < 4; ++kk) {
            const int g = kk * 4 + q;
            short8 a[4], bb[2];
#pragma unroll
            for (int rt = 0; rt < 4; ++rt)
                a[rt] = *(const short8*)(&As[(g * 128 + wy * 64 + rt * 16 + m) * 8]);
#pragma unroll
            for (int ct = 0; ct < 2; ++ct)
                bb[ct] = *(const short8*)(&Bs[(g * 128 + wx * 32 + ct * 16 + m) * 8]);
#pragma unroll
            for (int rt = 0; rt < 4; ++rt)
#pragma unroll
                for (int ct = 0; ct < 2; ++ct)
                    acc[rt][ct] = __builtin_amdgcn_mfma_f32_16x16x32_bf16(
                        a[rt], bb[ct], acc[rt][ct], 0, 0, 0);
        }

        // ---- branch-free hot epilogue; u = dist - POS_TH ----
        float scm[2], lc[2];
#pragma unroll
        for (int ct = 0; ct < 2; ++ct) {
            float2 v = lsqCS[cur][wx * 32 + ct * 16 + m];
            scm[ct] = v.x - POS_TH;
            lc[ct] = v.y;
        }

        float ptile = 0.f;
        float md = 1e30f;
#pragma unroll
        for (int rt = 0; rt < 4; ++rt) {
            float sr[4], lr[4];
#pragma unroll
            for (int reg = 0; reg < 4; ++reg) {
                float2 v = lsqRS[wy * 64 + rt * 16 + q * 4 + reg];
                sr[reg] = v.x; lr[reg] = v.y;
            }
#pragma unroll
            for (int ct = 0; ct < 2; ++ct) {
                f32x4 A = acc[rt][ct];
#pragma unroll
                for (int reg = 0; reg < 4; ++reg) {
                    float u = fmaf(A[reg], -2.f, sr[reg]) + scm[ct];
                    md = fminf(md, u);
                    float rel = fmaxf(u, 0.f);
                    ptile += (lr[reg] == lc[ct]) ? rel : 0.f;
                }
            }
        }

        // cold path: exact negatives (diag blocks trigger detector, find none)
        if (__any(md < (ALPHAF - POS_TH))) {
            const bool offd = (cbx != cby);
#pragma unroll
            for (int rt = 0; rt < 4; ++rt) {
                float sr[4], lr[4];
#pragma unroll
                for (int reg = 0; reg < 4; ++reg) {
                    float2 v = lsqRS[wy * 64 + rt * 16 + q * 4 + reg];
                    sr[reg] = v.x; lr[reg] = v.y;
                }
#pragma unroll
                for (int ct = 0; ct < 2; ++ct) {
                    f32x4 A = acc[rt][ct];
#pragma unroll
                    for (int reg = 0; reg < 4; ++reg) {
                        float u = fmaf(A[reg], -2.f, sr[reg]) + scm[ct];
                        if (lr[reg] != lc[ct] && u < (ALPHAF - POS_TH)) {
                            float gap = (ALPHAF - POS_TH) - u;
                            float wv = __expf(TF * gap);
                            int r = r0 + wy * 64 + rt * 16 + q * 4 + reg;
                            int c = c0 + wx * 32 + ct * 16 + m;
                            atomicAdd(&rowW[r], wv);
                            atomicAdd(&rowN[r], gap * wv);
                            if (offd) {
                                atomicAdd(&rowW[c], wv);
                                atomicAdd(&rowN[c], gap * wv);
                            }
                        }
                    }
                }
            }
        }

        pos += (cbx != cby) ? 2.f * ptile : ptile;

        if (havenext) {
            if (samerow) {
                if (t >= 128 && t < 256) lsqCS[cur ^ 1][t - 128] = vC;
                __syncthreads();   // drains B-DMA (issued a full tile of compute ago)
            } else {
                __syncthreads();   // all compute done: A band + lsqR now reusable
                const uint4* gA = ebfT4 + (size_t)nby * 2048;
                const uint4* gB = ebfT4 + (size_t)nbx * 2048;
                uint4* dB = Bs4[cur ^ 1];
#pragma unroll
                for (int j = 0; j < 4; ++j) {
                    int chunk = w * 4 + j;
                    __builtin_amdgcn_global_load_lds((guint*)(gA + chunk * 64 + lane),
                                                     (luint*)(&As4[chunk * 64]), 16, 0, 0);
                    __builtin_amdgcn_global_load_lds((guint*)(gB + chunk * 64 + lane),
                                                     (luint*)(dB + chunk * 64), 16, 0, 0);
                }
                if (t < 128) lsqRS[t] = lsq[nby * 128 + t];
                else if (t < 256) lsqCS[cur ^ 1][t - 128] = lsq[nbx * 128 + (t - 128)];
                __syncthreads();   // rare path (<=2x per block): drain A+B reload
            }
            cur ^= 1;
        }
        cby = nby; cbx = nbx;
    }

    // ---- block-reduce pos -> one atomic per block ----
#pragma unroll
    for (int off = 1; off < 64; off <<= 1) pos += __shfl_xor(pos, off, 64);
    __syncthreads();
    if (lane == 0) wred[w] = pos;
    __syncthreads();
    if (t == 0) {
        float s = 0.f;
#pragma unroll
        for (int ii = 0; ii < 8; ++ii) s += wred[ii];
        atomicAdd(posAcc, s);
        __threadfence();
        unsigned prev = atomicAdd(ctr, 1u);
        lastFlag = (prev == GRIDP - 1) ? 1 : 0;
    }
    __syncthreads();

    // ---- last block: fused finalize ----
    if (lastFlag) {
        __threadfence();
        if (t < NUM_CLASSES) { cw[t] = 0.f; cn[t] = 0.f; }
        __syncthreads();
        for (int i = t; i < N; i += 512) {
            int c = labels[i];
            float rw = __hip_atomic_load(&rowW[i], __ATOMIC_RELAXED, __HIP_MEMORY_SCOPE_AGENT);
            float rn = __hip_atomic_load(&rowN[i], __ATOMIC_RELAXED, __HIP_MEMORY_SCOPE_AGENT);
            atomicAdd(&cw[c], rw);
            atomicAdd(&cn[c], rn);
        }
        __syncthreads();
        if (t < NUM_CLASSES) {
            float v = (cw[t] > 0.f) ? (cn[t] / cw[t]) : 0.f;
#pragma unroll
            for (int off = 1; off < 64; off <<= 1) v += __shfl_xor(v, off, 64);
            if (t == 0) {
                float pt = __hip_atomic_load(posAcc, __ATOMIC_RELAXED, __HIP_MEMORY_SCOPE_AGENT);
                out[0] = pt + v;
                out[1] = (float)N;
            }
        }
    }
}

extern "C" void kernel_launch(void* const* d_in, const int* in_sizes, int n_in,
                              void* d_out, int out_size, void* d_ws, size_t ws_size,
                              hipStream_t stream) {
    const float* emb = (const float*)d_in[0];
    const int* labels = (const int*)d_in[1];
    float* out = (float*)d_out;
    float* ws = (float*)d_ws;

    float* posAcc = ws;
    unsigned int* ctr = (unsigned int*)(ws + 1);
    float* rowW = ws + 8;
    float* rowN = ws + 8 + N;
    float2* lsq = (float2*)(ws + 8 + 2 * N);
    uint4* ebfT4 = (uint4*)(ws + 8 + 4 * N);   // 16B-aligned

    prep_kernel<<<dim3(N / 64), dim3(256), 0, stream>>>(emb, labels, lsq, ebfT4, rowW, rowN, ws);

    pair_kernel<<<dim3(GRIDP), dim3(512), 0, stream>>>(ebfT4, lsq, labels, rowW, rowN,
                                                       posAcc, ctr, out);
}